// Round 1
// 774.629 us; speedup vs baseline: 1.0894x; 1.0894x over previous
//
#include <hip/hip_runtime.h>
#include <hip/hip_bf16.h>
#include <stdint.h>

typedef __hip_bfloat16 bf16;
typedef short bf16x8 __attribute__((ext_vector_type(8)));
typedef short s4v    __attribute__((ext_vector_type(4)));
typedef float f32x4  __attribute__((ext_vector_type(4)));

constexpr int B_  = 8;
constexpr int PQ_ = 900;
constexpr int C_  = 256;
constexpr int NH_ = 8;
constexpr int L_  = 4;
constexpr int P_  = 4;
constexpr int FF_ = 2048;
constexpr int DH_ = 32;
constexpr int PK_ = 20197;
constexpr int VLD = 960;    // VT row length (15 s-tiles of 64, zero-padded past 900)

__device__ __forceinline__ short f2b(float f) {
    __hip_bfloat16 h = __float2bfloat16(f);
    union { __hip_bfloat16 h; short s; } u; u.h = h; return u.s;
}
__device__ __forceinline__ float b2f(short s) {
    union { short s; __hip_bfloat16 h; } u; u.s = s; return __bfloat162float(u.h);
}

// ---------------------------------------------------------------------------
// Generalized batched MFMA GEMM (round-4, known good).
// C[batch][m][n] = act( scale * sum_k A[batch][m][k] * W[batch][n][k] + bias[n] )
// BM=64, BN=64*NF, BK=64; DBUF = register-prefetch double-buffered LDS,
// one barrier per K-iter.
// ---------------------------------------------------------------------------
template <int NF, bool DBUF, bool AF32, bool WF32, bool CF32, bool RELU>
__launch_bounds__(256)
__global__ void mfma_gemm(const void* __restrict__ Ap, const void* __restrict__ Wp,
                          const float* __restrict__ bias, void* __restrict__ Cp,
                          int Mb, int N, int K, int tilesM,
                          int ldA, int ldW, int ldC, int nbI,
                          int64_t sAo, int64_t sAi, int64_t sWo, int64_t sWi,
                          int64_t sCo, int64_t sCi, float scale)
{
    constexpr int BN  = 64 * NF;
    constexpr int LDR = 72;
    constexpr int NB  = DBUF ? 2 : 1;
    __shared__ short As[NB * 64 * LDR];
    __shared__ short Ws[NB * BN * LDR];

    const int tid   = threadIdx.x;
    const int batch = blockIdx.y / tilesM;
    const int m0    = (blockIdx.y % tilesM) * 64;
    const int n0    = blockIdx.x * BN;
    const int outer = batch / nbI, inner = batch % nbI;
    const int64_t offA = (int64_t)outer * sAo + (int64_t)inner * sAi;
    const int64_t offW = (int64_t)outer * sWo + (int64_t)inner * sWi;
    const int64_t offC = (int64_t)outer * sCo + (int64_t)inner * sCi;

    const int w = tid >> 6, lane = tid & 63;
    const int quad = lane >> 4, lrow = lane & 15;
    const int colbase = n0 + w * 16 * NF;

    const int sm  = tid >> 2;
    const int skb = (tid & 3) * 16;

    const int T = (K + 63) / 64;

    bf16x8 areg[2];
    bf16x8 wreg[2 * NF];

    auto stageA = [&](int t) {
        const int k0 = t * 64;
        const int gm = m0 + sm;
#pragma unroll
        for (int c = 0; c < 2; ++c) {
            const int k = k0 + skb + c * 8;
            bf16x8 pk = {0, 0, 0, 0, 0, 0, 0, 0};
            if (gm < Mb && k + 8 <= K) {
                if (AF32) {
                    const float* s = (const float*)Ap + offA + (int64_t)gm * ldA + k;
                    float4 u0 = *(const float4*)s;
                    float4 u1 = *(const float4*)(s + 4);
                    pk = (bf16x8){f2b(u0.x), f2b(u0.y), f2b(u0.z), f2b(u0.w),
                                  f2b(u1.x), f2b(u1.y), f2b(u1.z), f2b(u1.w)};
                } else {
                    pk = *(const bf16x8*)((const short*)Ap + offA + (int64_t)gm * ldA + k);
                }
            }
            areg[c] = pk;
        }
    };
    auto stageW = [&](int t) {
        const int k0 = t * 64;
#pragma unroll
        for (int j = 0; j < NF; ++j) {
            const int gn = n0 + j * 64 + sm;
#pragma unroll
            for (int c = 0; c < 2; ++c) {
                const int k = k0 + skb + c * 8;
                bf16x8 pk = {0, 0, 0, 0, 0, 0, 0, 0};
                if (gn < N && k + 8 <= K) {
                    if (WF32) {
                        const float* s = (const float*)Wp + offW + (int64_t)gn * ldW + k;
                        float4 u0 = *(const float4*)s;
                        float4 u1 = *(const float4*)(s + 4);
                        pk = (bf16x8){f2b(u0.x), f2b(u0.y), f2b(u0.z), f2b(u0.w),
                                      f2b(u1.x), f2b(u1.y), f2b(u1.z), f2b(u1.w)};
                    } else {
                        pk = *(const bf16x8*)((const short*)Wp + offW + (int64_t)gn * ldW + k);
                    }
                }
                wreg[j * 2 + c] = pk;
            }
        }
    };
    auto writeLDS = [&](int buf) {
#pragma unroll
        for (int c = 0; c < 2; ++c)
            *(bf16x8*)&As[(buf * 64 + sm) * LDR + skb + c * 8] = areg[c];
#pragma unroll
        for (int j = 0; j < NF; ++j)
#pragma unroll
            for (int c = 0; c < 2; ++c)
                *(bf16x8*)&Ws[(buf * BN + j * 64 + sm) * LDR + skb + c * 8] = wreg[j * 2 + c];
    };

    f32x4 acc[4][NF];
#pragma unroll
    for (int i = 0; i < 4; ++i)
#pragma unroll
        for (int j = 0; j < NF; ++j) acc[i][j] = (f32x4){0.f, 0.f, 0.f, 0.f};

    auto compute = [&](int buf) {
        bf16x8 a[4][2], bb[NF][2];
#pragma unroll
        for (int kh = 0; kh < 2; ++kh) {
#pragma unroll
            for (int mf = 0; mf < 4; ++mf)
                a[mf][kh] = *(const bf16x8*)&As[(buf * 64 + mf * 16 + lrow) * LDR + kh * 32 + quad * 8];
#pragma unroll
            for (int nf = 0; nf < NF; ++nf)
                bb[nf][kh] = *(const bf16x8*)&Ws[(buf * BN + w * 16 * NF + nf * 16 + lrow) * LDR + kh * 32 + quad * 8];
        }
#pragma unroll
        for (int kh = 0; kh < 2; ++kh)
#pragma unroll
            for (int mf = 0; mf < 4; ++mf)
#pragma unroll
                for (int nf = 0; nf < NF; ++nf)
                    acc[mf][nf] = __builtin_amdgcn_mfma_f32_16x16x32_bf16(a[mf][kh], bb[nf][kh], acc[mf][nf], 0, 0, 0);
    };

    if (DBUF) {
        stageA(0); stageW(0); writeLDS(0);
        __syncthreads();
        for (int t = 0; t < T; ++t) {
            const int cur = t & 1;
            if (t + 1 < T) { stageA(t + 1); stageW(t + 1); }
            compute(cur);
            if (t + 1 < T) {
                writeLDS(cur ^ 1);
                __syncthreads();
            }
        }
    } else {
        for (int t = 0; t < T; ++t) {
            stageA(t); stageW(t);
            if (t > 0) __syncthreads();
            writeLDS(0);
            __syncthreads();
            compute(0);
        }
    }

#pragma unroll
    for (int nf = 0; nf < NF; ++nf) {
        const int col = colbase + nf * 16 + lrow;
        if (col >= N) continue;
        const float bia = bias ? bias[col] : 0.f;
#pragma unroll
        for (int mf = 0; mf < 4; ++mf) {
            const int row0 = m0 + mf * 16 + quad * 4;
#pragma unroll
            for (int r = 0; r < 4; ++r) {
                const int rr = row0 + r;
                if (rr < Mb) {
                    float v = acc[mf][nf][r] * scale + bia;
                    if (RELU) v = fmaxf(v, 0.f);
                    const int64_t idx = offC + (int64_t)rr * ldC + col;
                    if (CF32) ((float*)Cp)[idx] = v;
                    else      ((short*)Cp)[idx] = f2b(v);
                }
            }
        }
    }
}

template <int NF, bool DBUF, bool AF32, bool WF32, bool CF32, bool RELU>
static void mfma_launch(const void* A, const void* W, const float* bias, void* Cp,
                        int nb, int nbI, int Mb, int N, int K,
                        int ldA, int ldW, int ldC,
                        int64_t sAo, int64_t sAi, int64_t sWo, int64_t sWi,
                        int64_t sCo, int64_t sCi, float scale, hipStream_t stream)
{
    int tilesM = (Mb + 63) / 64;
    dim3 grid((N + 64 * NF - 1) / (64 * NF), nb * tilesM);
    mfma_gemm<NF, DBUF, AF32, WF32, CF32, RELU><<<grid, 256, 0, stream>>>(
        A, W, bias, Cp, Mb, N, K, tilesM, ldA, ldW, ldC, nbI,
        sAo, sAi, sWo, sWi, sCo, sCi, scale);
}

// ---------------------------------------------------------------------------
// 32x32 tile transpose: dst[b][s][c] (bf16, row=256) = src[b*sbs + (c0+c)*ldS + s]
// ---------------------------------------------------------------------------
__launch_bounds__(256)
__global__ void transpose_kernel(const float* __restrict__ src, short* __restrict__ dst,
                                 int Scount, int ldS, int64_t sbs, int64_t dbs)
{
    const int tid = threadIdx.x;
    const int b = blockIdx.z;
    const int s0 = blockIdx.x * 32, c0 = blockIdx.y * 32;
    __shared__ float t[32][33];
    {
        const int c_l = tid >> 3, sq = (tid & 7) * 4;
        const int64_t base = (int64_t)b * sbs + (int64_t)(c0 + c_l) * ldS;
#pragma unroll
        for (int i = 0; i < 4; ++i) {
            const int s = s0 + sq + i;
            t[c_l][sq + i] = (s < Scount) ? src[base + s] : 0.f;
        }
    }
    __syncthreads();
    {
        const int s_l = tid >> 3, cq = (tid & 7) * 4;
        const int s = s0 + s_l;
        if (s < Scount) {
            s4v pk = {f2b(t[cq + 0][s_l]), f2b(t[cq + 1][s_l]),
                      f2b(t[cq + 2][s_l]), f2b(t[cq + 3][s_l])};
            *(s4v*)&dst[(int64_t)b * dbs + (int64_t)s * 256 + c0 + cq] = pk;
        }
    }
}

// ---------------------------------------------------------------------------
// VT[bh][d][s] (bf16, ld=960, s>=900 zero) from bf16 qkv (B*900, 768)
// ---------------------------------------------------------------------------
__launch_bounds__(256)
__global__ void vt_kernel(const short* __restrict__ qkv, short* __restrict__ VT)
{
    const int tid = threadIdx.x;
    const int bh = blockIdx.y, b = bh >> 3, h = bh & 7;
    const int s0 = blockIdx.x * 32;
    __shared__ short t[32][36];
    {
        const int s_l = tid >> 3, dq = (tid & 7) * 4;
        const int s = s0 + s_l;
        s4v pk = {0, 0, 0, 0};
        if (s < 900)
            pk = *(const s4v*)&qkv[((int64_t)(b * 900 + s)) * 768 + 512 + h * 32 + dq];
        *(s4v*)&t[s_l][dq] = pk;
    }
    __syncthreads();
    {
        const int d = tid >> 3, sq = (tid & 7) * 4;
        s4v pk = {t[sq + 0][d], t[sq + 1][d], t[sq + 2][d], t[sq + 3][d]};
        *(s4v*)&VT[((int64_t)bh * 32 + d) * VLD + s0 + sq] = pk;
    }
}

// ---------------------------------------------------------------------------
// Fused flash-style self-attention (round-4 known good).
// ---------------------------------------------------------------------------
__launch_bounds__(256)
__global__ void attn_fused(const short* __restrict__ qkv, const short* __restrict__ VT,
                           short* __restrict__ attno)
{
    __shared__ short Pl[4 * 16 * 72];
    const int tid = threadIdx.x;
    const int wv = tid >> 6, lane = tid & 63;
    const int quad = lane >> 4, lrow = lane & 15;
    const int bh = blockIdx.y, b = bh >> 3, h = bh & 7;
    const int q0 = blockIdx.x * 64 + wv * 16;
    const float iscale = 0.17677669529663687f; // 1/sqrt(32)

    bf16x8 aq = {0, 0, 0, 0, 0, 0, 0, 0};
    {
        const int q = q0 + lrow;
        if (q < 900)
            aq = *(const bf16x8*)&qkv[((int64_t)(b * 900 + q)) * 768 + h * 32 + quad * 8];
    }

    float mrow[4], lsum[4];
    f32x4 o[2] = {{0.f, 0.f, 0.f, 0.f}, {0.f, 0.f, 0.f, 0.f}};
#pragma unroll
    for (int r = 0; r < 4; ++r) { mrow[r] = -1e30f; lsum[r] = 0.f; }

    short* Pw = &Pl[wv * 16 * 72];

    for (int st = 0; st < 15; ++st) {
        const int s0 = st * 64;
        f32x4 sc[4];
#pragma unroll
        for (int nf = 0; nf < 4; ++nf) {
            const int s = s0 + nf * 16 + lrow;
            bf16x8 kb = {0, 0, 0, 0, 0, 0, 0, 0};
            if (s < 900)
                kb = *(const bf16x8*)&qkv[((int64_t)(b * 900 + s)) * 768 + 256 + h * 32 + quad * 8];
            sc[nf] = __builtin_amdgcn_mfma_f32_16x16x32_bf16(aq, kb, (f32x4){0.f, 0.f, 0.f, 0.f}, 0, 0, 0);
        }
#pragma unroll
        for (int nf = 0; nf < 4; ++nf) {
            const int s = s0 + nf * 16 + lrow;
            if (s >= 900) sc[nf] = (f32x4){-1e30f, -1e30f, -1e30f, -1e30f};
            else {
#pragma unroll
                for (int r = 0; r < 4; ++r) sc[nf][r] *= iscale;
            }
        }
        float alpha[4], ps[4][4], rsum[4];
#pragma unroll
        for (int r = 0; r < 4; ++r) {
            float tm = fmaxf(fmaxf(sc[0][r], sc[1][r]), fmaxf(sc[2][r], sc[3][r]));
#pragma unroll
            for (int off = 1; off < 16; off <<= 1)
                tm = fmaxf(tm, __shfl_xor(tm, off, 64));
            const float nm = fmaxf(mrow[r], tm);
            alpha[r] = __expf(mrow[r] - nm);
            mrow[r] = nm;
            float s4 = 0.f;
#pragma unroll
            for (int nf = 0; nf < 4; ++nf) {
                const float p = __expf(sc[nf][r] - nm);
                ps[nf][r] = p;
                s4 += p;
            }
#pragma unroll
            for (int off = 1; off < 16; off <<= 1)
                s4 += __shfl_xor(s4, off, 64);
            rsum[r] = s4;
        }
#pragma unroll
        for (int nf2 = 0; nf2 < 2; ++nf2)
#pragma unroll
            for (int r = 0; r < 4; ++r) o[nf2][r] *= alpha[r];
#pragma unroll
        for (int r = 0; r < 4; ++r) lsum[r] = lsum[r] * alpha[r] + rsum[r];
        // P -> per-wave LDS (C-layout scatter), read back as A-frags
#pragma unroll
        for (int nf = 0; nf < 4; ++nf)
#pragma unroll
            for (int r = 0; r < 4; ++r)
                Pw[(quad * 4 + r) * 72 + nf * 16 + lrow] = f2b(ps[nf][r]);
#pragma unroll
        for (int kh = 0; kh < 2; ++kh) {
            bf16x8 pa = *(const bf16x8*)&Pw[lrow * 72 + kh * 32 + quad * 8];
#pragma unroll
            for (int nf2 = 0; nf2 < 2; ++nf2) {
                const int d = nf2 * 16 + lrow;
                bf16x8 vb = *(const bf16x8*)&VT[((int64_t)bh * 32 + d) * VLD + s0 + kh * 32 + quad * 8];
                o[nf2] = __builtin_amdgcn_mfma_f32_16x16x32_bf16(pa, vb, o[nf2], 0, 0, 0);
            }
        }
    }
#pragma unroll
    for (int r = 0; r < 4; ++r) {
        const int q = q0 + quad * 4 + r;
        if (q < 900) {
            const float inv = 1.f / lsum[r];
#pragma unroll
            for (int nf2 = 0; nf2 < 2; ++nf2)
                attno[((int64_t)(b * 900 + q)) * 256 + h * 32 + nf2 * 16 + lrow] = f2b(o[nf2][r] * inv);
        }
    }
}

// ---------------------------------------------------------------------------
// Residual + LayerNorm over C=256, one block per (b,t).
// MODE 0: res = query (B,C,PQ) fp32 transposed-read; out q1 fp32 + q1b bf16
// MODE 1: res = q1 fp32 (BT,C);                      out q2nb bf16 only
// MODE 2: res = q2nb bf16 (BT,C);                    out d_out fp32 (B,C,PQ)
// ---------------------------------------------------------------------------
template <int MODE>
__launch_bounds__(256)
__global__ void ln_kernel(const float* __restrict__ y, const void* __restrict__ res,
                          const float* __restrict__ g, const float* __restrict__ be,
                          float* __restrict__ out_f, short* __restrict__ out_b)
{
    const int bt = blockIdx.x;
    const int b = bt / PQ_, t = bt % PQ_;
    const int c = threadIdx.x;

    float r;
    if (MODE == 0)      r = ((const float*)res)[((int64_t)b * C_ + c) * PQ_ + t];
    else if (MODE == 1) r = ((const float*)res)[(int64_t)bt * C_ + c];
    else                r = b2f(((const short*)res)[(int64_t)bt * C_ + c]);
    const float v = r + y[(int64_t)bt * C_ + c];

    __shared__ float s1[256], s2[256];
    s1[c] = v; s2[c] = v * v;
    __syncthreads();
    for (int st = 128; st > 0; st >>= 1) {
        if (c < st) { s1[c] += s1[c + st]; s2[c] += s2[c + st]; }
        __syncthreads();
    }
    const float mean = s1[0] * (1.f / C_);
    const float var  = s2[0] * (1.f / C_) - mean * mean;
    const float o = (v - mean) * rsqrtf(var + 1e-5f) * g[c] + be[c];

    if (MODE == 0) { out_f[(int64_t)bt * C_ + c] = o; out_b[(int64_t)bt * C_ + c] = f2b(o); }
    else if (MODE == 1) out_b[(int64_t)bt * C_ + c] = f2b(o);
    else out_f[((int64_t)b * C_ + c) * PQ_ + t] = o;
}

// ---------------------------------------------------------------------------
// Fused MS-deformable sampling — all 4 levels in one kernel.
// value is the full (B, PK, 256) bf16 projected value (layout s*256 + h*32 + d,
// identical to per-level (HW, NH, DH)). Softmax over Law computed once; fp32
// accumulation across levels; single bf16 samp write (no RMW).
// ---------------------------------------------------------------------------
__launch_bounds__(256)
__global__ void deform_kernel(const float* __restrict__ offb, const float* __restrict__ awl,
                              const float* __restrict__ refp, const short* __restrict__ value,
                              short* __restrict__ samp)
{
    const int bt = blockIdx.x;
    const int b = bt / PQ_;
    const int tid = threadIdx.x;
    const int h = tid >> 5, d = tid & 31;

    __shared__ float Loff[256];
    __shared__ float Law[128];
    __shared__ float Lref[8];

    Loff[tid] = offb[(int64_t)bt * 256 + tid];
    if (tid < 128) Law[tid] = awl[(int64_t)bt * 128 + tid];
    if (tid < 8)   Lref[tid] = refp[(int64_t)bt * 8 + tid];
    __syncthreads();

    float m = -1e30f;
#pragma unroll
    for (int i = 0; i < 16; ++i) m = fmaxf(m, Law[h * 16 + i]);
    float s = 0.f;
#pragma unroll
    for (int i = 0; i < 16; ++i) s += __expf(Law[h * 16 + i] - m);
    const float invs = 1.f / s;

    const int HLc[4] = {100, 50, 25, 13};
    const int WLc[4] = {152, 76, 38, 19};
    const int STc[4] = {0, 15200, 19000, 19950};

    float acc = 0.f;
#pragma unroll
    for (int l = 0; l < L_; ++l) {
        const int Hl = HLc[l], Wl = WLc[l], st0 = STc[l];
        const float fx = Lref[l * 2 + 0], fy = Lref[l * 2 + 1];
#pragma unroll
        for (int p = 0; p < P_; ++p) {
            const float ox = Loff[h * 32 + l * 8 + p * 2 + 0];
            const float oy = Loff[h * 32 + l * 8 + p * 2 + 1];
            const float x = (fx + ox / (float)Wl) * (float)Wl - 0.5f;
            const float y = (fy + oy / (float)Hl) * (float)Hl - 0.5f;
            const float x0f = floorf(x), y0f = floorf(y);
            const int x0 = (int)x0f, y0 = (int)y0f;
            const float lw = x - x0f, lh = y - y0f;
            const float w00 = (1.f - lw) * (1.f - lh), w10 = lw * (1.f - lh);
            const float w01 = (1.f - lw) * lh,         w11 = lw * lh;
            const float aww = __expf(Law[h * 16 + l * 4 + p] - m) * invs;

            float sv = 0.f;
            int ix, iy; float w;
#pragma unroll
            for (int cidx = 0; cidx < 4; ++cidx) {
                if (cidx == 0) { ix = x0;     iy = y0;     w = w00; }
                if (cidx == 1) { ix = x0 + 1; iy = y0;     w = w10; }
                if (cidx == 2) { ix = x0;     iy = y0 + 1; w = w01; }
                if (cidx == 3) { ix = x0 + 1; iy = y0 + 1; w = w11; }
                if (ix >= 0 && ix < Wl && iy >= 0 && iy < Hl) {
                    const int64_t vi = ((int64_t)(b * PK_ + st0 + iy * Wl + ix)) * 256 + h * 32 + d;
                    sv += w * b2f(value[vi]);
                }
            }
            acc += sv * aww;
        }
    }
    samp[(int64_t)bt * 256 + tid] = f2b(acc);
}

// ---------------------------------------------------------------------------
extern "C" void kernel_launch(void* const* d_in, const int* in_sizes, int n_in,
                              void* d_out, int out_size, void* d_ws, size_t ws_size,
                              hipStream_t stream)
{
    const float* query = (const float*)d_in[0];
    const float* key   = (const float*)d_in[1];
    const float* refp  = (const float*)d_in[4];
    const float* W_in  = (const float*)d_in[5];
    const float* b_in  = (const float*)d_in[6];
    const float* W_out = (const float*)d_in[7];
    const float* b_out = (const float*)d_in[8];
    const float* W_off = (const float*)d_in[9];
    const float* b_off = (const float*)d_in[10];
    const float* W_aw  = (const float*)d_in[11];
    const float* b_aw  = (const float*)d_in[12];
    const float* W_v   = (const float*)d_in[13];
    const float* b_v   = (const float*)d_in[14];
    const float* W_o   = (const float*)d_in[15];
    const float* b_o   = (const float*)d_in[16];
    const float* W1    = (const float*)d_in[17];
    const float* b1    = (const float*)d_in[18];
    const float* W2    = (const float*)d_in[19];
    const float* b2    = (const float*)d_in[20];
    const float* g1    = (const float*)d_in[21];
    const float* be1   = (const float*)d_in[22];
    const float* g2    = (const float*)d_in[23];
    const float* be2   = (const float*)d_in[24];
    const float* g3    = (const float*)d_in[25];
    const float* be3   = (const float*)d_in[26];

    // Workspace plan (fill evidence: ws >= ~660 MB; we use ~250 MB):
    //  X [62,259,200]: {qkv bf16 11.1M | queryT 3.7M | VT 3.9M | attno 3.7M}
    //                  -> later ffh 29.5M
    //  Y: proj -> offb -> proj2 -> ffo ; Z1: q1 ; Wa: q1b -> samp ; Wb: awl -> q2nb
    //  KT:  keyT  (B*PK,256) bf16  = 82,726,912 B
    //  VAL: value (B*PK,256) bf16  = 82,726,912 B  (out-of-place value GEMM)
    char* X  = (char*)d_ws;
    char* Yb = X + 62259200;
    char* Z1 = Yb + 7372800;
    char* Wa = Z1 + 7372800;
    char* Wb = Wa + 3686400;
    char* KT = Wb + 3686400;
    char* VA = KT + 82726912;

    short* qkvb   = (short*)X;                 // (B*900, 768) bf16
    short* queryT = (short*)(X + 11059200);
    short* VT     = (short*)(X + 14745600);    // 64*32*960*2 = 3,932,160
    short* attno  = (short*)(X + 18677760);
    short* ffh    = (short*)X;
    float* proj   = (float*)Yb;
    float* offb   = (float*)Yb;
    float* proj2  = (float*)Yb;
    float* ffo    = (float*)Yb;
    float* q1     = (float*)Z1;
    short* q1b    = (short*)Wa;
    short* samp   = (short*)Wa;
    float* awl    = (float*)Wb;
    short* q2nb   = (short*)Wb;
    short* keyT   = (short*)KT;
    short* value  = (short*)VA;

    // 1. queryT = bf16 transpose of query
    transpose_kernel<<<dim3(29, 8, B_), 256, 0, stream>>>(query, queryT, PQ_, PQ_,
                                                          (int64_t)C_ * PQ_, (int64_t)PQ_ * C_);
    // 2. qkv = queryT @ W_in^T + b_in  (bf16 out)
    mfma_launch<1, true, false, true, false, false>(queryT, W_in, b_in, qkvb, 1, 1, B_ * PQ_, 768, 256,
                                                    256, 256, 768, 0, 0, 0, 0, 0, 0, 1.f, stream);
    // 3. VT (zero-padded to 960)
    vt_kernel<<<dim3(30, 64), 256, 0, stream>>>(qkvb, VT);
    // 4. fused flash attention -> attno (bf16)
    attn_fused<<<dim3(15, 64), 256, 0, stream>>>(qkvb, VT, attno);
    // 5. proj = attno @ W_out^T + b_out
    mfma_launch<1, true, false, true, true, false>(attno, W_out, b_out, proj, 1, 1, B_ * PQ_, 256, 256,
                                                   256, 256, 256, 0, 0, 0, 0, 0, 0, 1.f, stream);
    // 6. q1 = LN(x + proj)  (fp32 + bf16)
    ln_kernel<0><<<B_ * PQ_, 256, 0, stream>>>(proj, query, g1, be1, q1, q1b);
    // 7. offsets / attention-weight logits
    mfma_launch<1, true, false, true, true, false>(q1b, W_off, b_off, offb, 1, 1, B_ * PQ_, 256, 256,
                                                   256, 256, 256, 0, 0, 0, 0, 0, 0, 1.f, stream);
    mfma_launch<1, true, false, true, true, false>(q1b, W_aw, b_aw, awl, 1, 1, B_ * PQ_, 128, 256,
                                                   256, 256, 128, 0, 0, 0, 0, 0, 0, 1.f, stream);
    // 8. keyT = bf16 transpose of ALL of key (levels are contiguous PK slices);
    //    value = keyT @ W_v^T + b_v (single out-of-place DBUF GEMM, M=161576);
    //    fused 4-level deform accumulate -> samp
    transpose_kernel<<<dim3((PK_ + 31) / 32, 8, B_), 256, 0, stream>>>(
        key, keyT, PK_, PK_, (int64_t)C_ * PK_, (int64_t)PK_ * 256);
    mfma_launch<1, true, false, true, false, false>(keyT, W_v, b_v, value, 1, 1, B_ * PK_, 256, 256,
                                                    256, 256, 256, 0, 0, 0, 0, 0, 0, 1.f, stream);
    deform_kernel<<<B_ * PQ_, 256, 0, stream>>>(offb, awl, refp, value, samp);
    // 9. proj2 = samp @ W_o^T + b_o
    mfma_launch<1, true, false, true, true, false>(samp, W_o, b_o, proj2, 1, 1, B_ * PQ_, 256, 256,
                                                   256, 256, 256, 0, 0, 0, 0, 0, 0, 1.f, stream);
    // 10. q2nb = LN(q1 + proj2)  (bf16)
    ln_kernel<1><<<B_ * PQ_, 256, 0, stream>>>(proj2, q1, g2, be2, nullptr, q2nb);
    // 11. ffh = relu(q2nb @ W1^T + b1)  (bf16)
    mfma_launch<1, true, false, true, false, true>(q2nb, W1, b1, ffh, 1, 1, B_ * PQ_, FF_, 256,
                                                   256, 256, FF_, 0, 0, 0, 0, 0, 0, 1.f, stream);
    // 12. ffo = ffh @ W2^T + b2
    mfma_launch<1, true, false, true, true, false>(ffh, W2, b2, ffo, 1, 1, B_ * PQ_, 256, FF_,
                                                   FF_, FF_, 256, 0, 0, 0, 0, 0, 0, 1.f, stream);
    // 13. d_out = LN(q2nb + ffo), transposed to (B,C,PQ)
    ln_kernel<2><<<B_ * PQ_, 256, 0, stream>>>(ffo, q2nb, g3, be3, (float*)d_out, nullptr);

    (void)in_sizes; (void)n_in; (void)out_size; (void)ws_size;
}

// Round 2
// 739.225 us; speedup vs baseline: 1.1416x; 1.0479x over previous
//
#include <hip/hip_runtime.h>
#include <hip/hip_bf16.h>
#include <stdint.h>

typedef __hip_bfloat16 bf16;
typedef short bf16x8 __attribute__((ext_vector_type(8)));
typedef short s4v    __attribute__((ext_vector_type(4)));
typedef float f32x4  __attribute__((ext_vector_type(4)));

constexpr int B_  = 8;
constexpr int PQ_ = 900;
constexpr int C_  = 256;
constexpr int NH_ = 8;
constexpr int L_  = 4;
constexpr int P_  = 4;
constexpr int FF_ = 2048;
constexpr int DH_ = 32;
constexpr int PK_ = 20197;
constexpr int VLD = 960;    // VT row length (15 s-tiles of 64, zero-padded past 900)

__device__ __forceinline__ short f2b(float f) {
    __hip_bfloat16 h = __float2bfloat16(f);
    union { __hip_bfloat16 h; short s; } u; u.h = h; return u.s;
}
__device__ __forceinline__ float b2f(short s) {
    union { short s; __hip_bfloat16 h; } u; u.s = s; return __bfloat162float(u.h);
}

// ---------------------------------------------------------------------------
// Batched fp32 -> bf16 weight conversion, one launch for all 8 weight mats.
// Segment table (elements): W_in 196608 | W_out 65536 | W_off 65536 |
// W_aw 32768 | W_v 65536 | W_o 65536 | W1 524288 | W2 524288  (total 1540096)
// ---------------------------------------------------------------------------
__launch_bounds__(256)
__global__ void wcvt_kernel(const float* __restrict__ p0, const float* __restrict__ p1,
                            const float* __restrict__ p2, const float* __restrict__ p3,
                            const float* __restrict__ p4, const float* __restrict__ p5,
                            const float* __restrict__ p6, const float* __restrict__ p7,
                            short* __restrict__ dst)
{
    const int g = (blockIdx.x * 256 + threadIdx.x) * 4;
    const float* src; int off;
    if      (g < 196608)  { src = p0; off = 0; }
    else if (g < 262144)  { src = p1; off = 196608; }
    else if (g < 327680)  { src = p2; off = 262144; }
    else if (g < 360448)  { src = p3; off = 327680; }
    else if (g < 425984)  { src = p4; off = 360448; }
    else if (g < 491520)  { src = p5; off = 425984; }
    else if (g < 1015808) { src = p6; off = 491520; }
    else                  { src = p7; off = 1015808; }
    float4 v = *(const float4*)(src + (g - off));
    s4v pk = {f2b(v.x), f2b(v.y), f2b(v.z), f2b(v.w)};
    *(s4v*)&dst[g] = pk;
}

// ---------------------------------------------------------------------------
// Generalized batched MFMA GEMM (known good). W is now always bf16 (WF32 kept
// for flexibility but unused). BM=64, BN=64*NF, BK=64; DBUF = register-
// prefetch double-buffered LDS, one barrier per K-iter.
// ---------------------------------------------------------------------------
template <int NF, bool DBUF, bool AF32, bool WF32, bool CF32, bool RELU>
__launch_bounds__(256)
__global__ void mfma_gemm(const void* __restrict__ Ap, const void* __restrict__ Wp,
                          const float* __restrict__ bias, void* __restrict__ Cp,
                          int Mb, int N, int K, int tilesM,
                          int ldA, int ldW, int ldC, int nbI,
                          int64_t sAo, int64_t sAi, int64_t sWo, int64_t sWi,
                          int64_t sCo, int64_t sCi, float scale)
{
    constexpr int BN  = 64 * NF;
    constexpr int LDR = 72;
    constexpr int NB  = DBUF ? 2 : 1;
    __shared__ short As[NB * 64 * LDR];
    __shared__ short Ws[NB * BN * LDR];

    const int tid   = threadIdx.x;
    const int batch = blockIdx.y / tilesM;
    const int m0    = (blockIdx.y % tilesM) * 64;
    const int n0    = blockIdx.x * BN;
    const int outer = batch / nbI, inner = batch % nbI;
    const int64_t offA = (int64_t)outer * sAo + (int64_t)inner * sAi;
    const int64_t offW = (int64_t)outer * sWo + (int64_t)inner * sWi;
    const int64_t offC = (int64_t)outer * sCo + (int64_t)inner * sCi;

    const int w = tid >> 6, lane = tid & 63;
    const int quad = lane >> 4, lrow = lane & 15;
    const int colbase = n0 + w * 16 * NF;

    const int sm  = tid >> 2;
    const int skb = (tid & 3) * 16;

    const int T = (K + 63) / 64;

    bf16x8 areg[2];
    bf16x8 wreg[2 * NF];

    auto stageA = [&](int t) {
        const int k0 = t * 64;
        const int gm = m0 + sm;
#pragma unroll
        for (int c = 0; c < 2; ++c) {
            const int k = k0 + skb + c * 8;
            bf16x8 pk = {0, 0, 0, 0, 0, 0, 0, 0};
            if (gm < Mb && k + 8 <= K) {
                if (AF32) {
                    const float* s = (const float*)Ap + offA + (int64_t)gm * ldA + k;
                    float4 u0 = *(const float4*)s;
                    float4 u1 = *(const float4*)(s + 4);
                    pk = (bf16x8){f2b(u0.x), f2b(u0.y), f2b(u0.z), f2b(u0.w),
                                  f2b(u1.x), f2b(u1.y), f2b(u1.z), f2b(u1.w)};
                } else {
                    pk = *(const bf16x8*)((const short*)Ap + offA + (int64_t)gm * ldA + k);
                }
            }
            areg[c] = pk;
        }
    };
    auto stageW = [&](int t) {
        const int k0 = t * 64;
#pragma unroll
        for (int j = 0; j < NF; ++j) {
            const int gn = n0 + j * 64 + sm;
#pragma unroll
            for (int c = 0; c < 2; ++c) {
                const int k = k0 + skb + c * 8;
                bf16x8 pk = {0, 0, 0, 0, 0, 0, 0, 0};
                if (gn < N && k + 8 <= K) {
                    if (WF32) {
                        const float* s = (const float*)Wp + offW + (int64_t)gn * ldW + k;
                        float4 u0 = *(const float4*)s;
                        float4 u1 = *(const float4*)(s + 4);
                        pk = (bf16x8){f2b(u0.x), f2b(u0.y), f2b(u0.z), f2b(u0.w),
                                      f2b(u1.x), f2b(u1.y), f2b(u1.z), f2b(u1.w)};
                    } else {
                        pk = *(const bf16x8*)((const short*)Wp + offW + (int64_t)gn * ldW + k);
                    }
                }
                wreg[j * 2 + c] = pk;
            }
        }
    };
    auto writeLDS = [&](int buf) {
#pragma unroll
        for (int c = 0; c < 2; ++c)
            *(bf16x8*)&As[(buf * 64 + sm) * LDR + skb + c * 8] = areg[c];
#pragma unroll
        for (int j = 0; j < NF; ++j)
#pragma unroll
            for (int c = 0; c < 2; ++c)
                *(bf16x8*)&Ws[(buf * BN + j * 64 + sm) * LDR + skb + c * 8] = wreg[j * 2 + c];
    };

    f32x4 acc[4][NF];
#pragma unroll
    for (int i = 0; i < 4; ++i)
#pragma unroll
        for (int j = 0; j < NF; ++j) acc[i][j] = (f32x4){0.f, 0.f, 0.f, 0.f};

    auto compute = [&](int buf) {
        bf16x8 a[4][2], bb[NF][2];
#pragma unroll
        for (int kh = 0; kh < 2; ++kh) {
#pragma unroll
            for (int mf = 0; mf < 4; ++mf)
                a[mf][kh] = *(const bf16x8*)&As[(buf * 64 + mf * 16 + lrow) * LDR + kh * 32 + quad * 8];
#pragma unroll
            for (int nf = 0; nf < NF; ++nf)
                bb[nf][kh] = *(const bf16x8*)&Ws[(buf * BN + w * 16 * NF + nf * 16 + lrow) * LDR + kh * 32 + quad * 8];
        }
#pragma unroll
        for (int kh = 0; kh < 2; ++kh)
#pragma unroll
            for (int mf = 0; mf < 4; ++mf)
#pragma unroll
                for (int nf = 0; nf < NF; ++nf)
                    acc[mf][nf] = __builtin_amdgcn_mfma_f32_16x16x32_bf16(a[mf][kh], bb[nf][kh], acc[mf][nf], 0, 0, 0);
    };

    if (DBUF) {
        stageA(0); stageW(0); writeLDS(0);
        __syncthreads();
        for (int t = 0; t < T; ++t) {
            const int cur = t & 1;
            if (t + 1 < T) { stageA(t + 1); stageW(t + 1); }
            compute(cur);
            if (t + 1 < T) {
                writeLDS(cur ^ 1);
                __syncthreads();
            }
        }
    } else {
        for (int t = 0; t < T; ++t) {
            stageA(t); stageW(t);
            if (t > 0) __syncthreads();
            writeLDS(0);
            __syncthreads();
            compute(0);
        }
    }

#pragma unroll
    for (int nf = 0; nf < NF; ++nf) {
        const int col = colbase + nf * 16 + lrow;
        if (col >= N) continue;
        const float bia = bias ? bias[col] : 0.f;
#pragma unroll
        for (int mf = 0; mf < 4; ++mf) {
            const int row0 = m0 + mf * 16 + quad * 4;
#pragma unroll
            for (int r = 0; r < 4; ++r) {
                const int rr = row0 + r;
                if (rr < Mb) {
                    float v = acc[mf][nf][r] * scale + bia;
                    if (RELU) v = fmaxf(v, 0.f);
                    const int64_t idx = offC + (int64_t)rr * ldC + col;
                    if (CF32) ((float*)Cp)[idx] = v;
                    else      ((short*)Cp)[idx] = f2b(v);
                }
            }
        }
    }
}

template <int NF, bool DBUF, bool AF32, bool WF32, bool CF32, bool RELU>
static void mfma_launch(const void* A, const void* W, const float* bias, void* Cp,
                        int nb, int nbI, int Mb, int N, int K,
                        int ldA, int ldW, int ldC,
                        int64_t sAo, int64_t sAi, int64_t sWo, int64_t sWi,
                        int64_t sCo, int64_t sCi, float scale, hipStream_t stream)
{
    int tilesM = (Mb + 63) / 64;
    dim3 grid((N + 64 * NF - 1) / (64 * NF), nb * tilesM);
    mfma_gemm<NF, DBUF, AF32, WF32, CF32, RELU><<<grid, 256, 0, stream>>>(
        A, W, bias, Cp, Mb, N, K, tilesM, ldA, ldW, ldC, nbI,
        sAo, sAi, sWo, sWi, sCo, sCi, scale);
}

// ---------------------------------------------------------------------------
// Value projection: C[m][n] = A[m][k] * W[n][k] + bias[n],  M=B*PK, N=K=256.
// W half (128 n-rows, bf16) resident in LDS (64 KB, XOR-swizzled 16B slots ->
// conflict-free b128 reads). A-fragments loaded DIRECTLY from global (16B/lane)
// -- no per-K-iter LDS round trip, no barriers in the main loop. Each block
// processes 4 M-tiles of 64 rows per W stage. grid = (2, ceil(tiles/4)).
// ---------------------------------------------------------------------------
__launch_bounds__(256)
__global__ void vproj_kernel(const short* __restrict__ A, const short* __restrict__ Wb,
                             const float* __restrict__ bias, short* __restrict__ Cp,
                             int Mb, int nTiles)
{
    __shared__ short Ws[128 * 256];   // 64 KB
    const int tid = threadIdx.x;
    const int n0 = blockIdx.x * 128;
    const int w = tid >> 6, lane = tid & 63;
    const int quad = lane >> 4, lrow = lane & 15;

    // ---- stage W half: row n (0..127), half hk covers 16 of 32 16B-slots.
    // swizzled slot = slot ^ (n & 7)  (bijective within row; balanced banks)
    {
        const int n = tid >> 1, hk = tid & 1;
        const int64_t src = (int64_t)(n0 + n) * 256 + hk * 128;
#pragma unroll
        for (int j = 0; j < 16; ++j) {
            const int slot = hk * 16 + j;
            bf16x8 pk = *(const bf16x8*)&Wb[src + j * 8];
            *(bf16x8*)((char*)Ws + n * 512 + ((slot ^ (n & 7)) << 4)) = pk;
        }
    }
    __syncthreads();

    const int nbase = w * 32;   // wave's 32 columns within the 128
    float bia[2];
#pragma unroll
    for (int nf = 0; nf < 2; ++nf) bia[nf] = bias[n0 + nbase + nf * 16 + lrow];

    for (int it = 0; it < 4; ++it) {
        const int ti = blockIdx.y * 4 + it;
        if (ti >= nTiles) break;
        const int m0 = ti * 64;

        f32x4 acc[4][2];
#pragma unroll
        for (int mf = 0; mf < 4; ++mf)
#pragma unroll
            for (int nf = 0; nf < 2; ++nf) acc[mf][nf] = (f32x4){0.f, 0.f, 0.f, 0.f};

#pragma unroll
        for (int kh = 0; kh < 8; ++kh) {
            bf16x8 a[4];
#pragma unroll
            for (int mf = 0; mf < 4; ++mf) {
                const int gm = m0 + mf * 16 + lrow;
                a[mf] = (gm < Mb)
                    ? *(const bf16x8*)&A[(int64_t)gm * 256 + kh * 32 + quad * 8]
                    : (bf16x8){0, 0, 0, 0, 0, 0, 0, 0};
            }
            bf16x8 b[2];
#pragma unroll
            for (int nf = 0; nf < 2; ++nf) {
                const int n = nbase + nf * 16 + lrow;
                b[nf] = *(const bf16x8*)((const char*)Ws + n * 512 +
                                         ((((kh << 2) | quad) ^ (lrow & 7)) << 4));
            }
#pragma unroll
            for (int mf = 0; mf < 4; ++mf)
#pragma unroll
                for (int nf = 0; nf < 2; ++nf)
                    acc[mf][nf] = __builtin_amdgcn_mfma_f32_16x16x32_bf16(a[mf], b[nf], acc[mf][nf], 0, 0, 0);
        }

#pragma unroll
        for (int nf = 0; nf < 2; ++nf) {
            const int col = n0 + nbase + nf * 16 + lrow;
#pragma unroll
            for (int mf = 0; mf < 4; ++mf) {
#pragma unroll
                for (int r = 0; r < 4; ++r) {
                    const int rr = m0 + mf * 16 + quad * 4 + r;
                    if (rr < Mb)
                        Cp[(int64_t)rr * 256 + col] = f2b(acc[mf][nf][r] + bia[nf]);
                }
            }
        }
    }
}

// ---------------------------------------------------------------------------
// 32x32 tile transpose: dst[b][s][c] (bf16, row=256) = src[b*sbs + (c0+c)*ldS + s]
// ---------------------------------------------------------------------------
__launch_bounds__(256)
__global__ void transpose_kernel(const float* __restrict__ src, short* __restrict__ dst,
                                 int Scount, int ldS, int64_t sbs, int64_t dbs)
{
    const int tid = threadIdx.x;
    const int b = blockIdx.z;
    const int s0 = blockIdx.x * 32, c0 = blockIdx.y * 32;
    __shared__ float t[32][33];
    {
        const int c_l = tid >> 3, sq = (tid & 7) * 4;
        const int64_t base = (int64_t)b * sbs + (int64_t)(c0 + c_l) * ldS;
#pragma unroll
        for (int i = 0; i < 4; ++i) {
            const int s = s0 + sq + i;
            t[c_l][sq + i] = (s < Scount) ? src[base + s] : 0.f;
        }
    }
    __syncthreads();
    {
        const int s_l = tid >> 3, cq = (tid & 7) * 4;
        const int s = s0 + s_l;
        if (s < Scount) {
            s4v pk = {f2b(t[cq + 0][s_l]), f2b(t[cq + 1][s_l]),
                      f2b(t[cq + 2][s_l]), f2b(t[cq + 3][s_l])};
            *(s4v*)&dst[(int64_t)b * dbs + (int64_t)s * 256 + c0 + cq] = pk;
        }
    }
}

// ---------------------------------------------------------------------------
// VT[bh][d][s] (bf16, ld=960, s>=900 zero) from bf16 qkv (B*900, 768)
// ---------------------------------------------------------------------------
__launch_bounds__(256)
__global__ void vt_kernel(const short* __restrict__ qkv, short* __restrict__ VT)
{
    const int tid = threadIdx.x;
    const int bh = blockIdx.y, b = bh >> 3, h = bh & 7;
    const int s0 = blockIdx.x * 32;
    __shared__ short t[32][36];
    {
        const int s_l = tid >> 3, dq = (tid & 7) * 4;
        const int s = s0 + s_l;
        s4v pk = {0, 0, 0, 0};
        if (s < 900)
            pk = *(const s4v*)&qkv[((int64_t)(b * 900 + s)) * 768 + 512 + h * 32 + dq];
        *(s4v*)&t[s_l][dq] = pk;
    }
    __syncthreads();
    {
        const int d = tid >> 3, sq = (tid & 7) * 4;
        s4v pk = {t[sq + 0][d], t[sq + 1][d], t[sq + 2][d], t[sq + 3][d]};
        *(s4v*)&VT[((int64_t)bh * 32 + d) * VLD + s0 + sq] = pk;
    }
}

// ---------------------------------------------------------------------------
// Fused flash-style self-attention (known good).
// ---------------------------------------------------------------------------
__launch_bounds__(256)
__global__ void attn_fused(const short* __restrict__ qkv, const short* __restrict__ VT,
                           short* __restrict__ attno)
{
    __shared__ short Pl[4 * 16 * 72];
    const int tid = threadIdx.x;
    const int wv = tid >> 6, lane = tid & 63;
    const int quad = lane >> 4, lrow = lane & 15;
    const int bh = blockIdx.y, b = bh >> 3, h = bh & 7;
    const int q0 = blockIdx.x * 64 + wv * 16;
    const float iscale = 0.17677669529663687f; // 1/sqrt(32)

    bf16x8 aq = {0, 0, 0, 0, 0, 0, 0, 0};
    {
        const int q = q0 + lrow;
        if (q < 900)
            aq = *(const bf16x8*)&qkv[((int64_t)(b * 900 + q)) * 768 + h * 32 + quad * 8];
    }

    float mrow[4], lsum[4];
    f32x4 o[2] = {{0.f, 0.f, 0.f, 0.f}, {0.f, 0.f, 0.f, 0.f}};
#pragma unroll
    for (int r = 0; r < 4; ++r) { mrow[r] = -1e30f; lsum[r] = 0.f; }

    short* Pw = &Pl[wv * 16 * 72];

    for (int st = 0; st < 15; ++st) {
        const int s0 = st * 64;
        f32x4 sc[4];
#pragma unroll
        for (int nf = 0; nf < 4; ++nf) {
            const int s = s0 + nf * 16 + lrow;
            bf16x8 kb = {0, 0, 0, 0, 0, 0, 0, 0};
            if (s < 900)
                kb = *(const bf16x8*)&qkv[((int64_t)(b * 900 + s)) * 768 + 256 + h * 32 + quad * 8];
            sc[nf] = __builtin_amdgcn_mfma_f32_16x16x32_bf16(aq, kb, (f32x4){0.f, 0.f, 0.f, 0.f}, 0, 0, 0);
        }
#pragma unroll
        for (int nf = 0; nf < 4; ++nf) {
            const int s = s0 + nf * 16 + lrow;
            if (s >= 900) sc[nf] = (f32x4){-1e30f, -1e30f, -1e30f, -1e30f};
            else {
#pragma unroll
                for (int r = 0; r < 4; ++r) sc[nf][r] *= iscale;
            }
        }
        float alpha[4], ps[4][4], rsum[4];
#pragma unroll
        for (int r = 0; r < 4; ++r) {
            float tm = fmaxf(fmaxf(sc[0][r], sc[1][r]), fmaxf(sc[2][r], sc[3][r]));
#pragma unroll
            for (int off = 1; off < 16; off <<= 1)
                tm = fmaxf(tm, __shfl_xor(tm, off, 64));
            const float nm = fmaxf(mrow[r], tm);
            alpha[r] = __expf(mrow[r] - nm);
            mrow[r] = nm;
            float s4 = 0.f;
#pragma unroll
            for (int nf = 0; nf < 4; ++nf) {
                const float p = __expf(sc[nf][r] - nm);
                ps[nf][r] = p;
                s4 += p;
            }
#pragma unroll
            for (int off = 1; off < 16; off <<= 1)
                s4 += __shfl_xor(s4, off, 64);
            rsum[r] = s4;
        }
#pragma unroll
        for (int nf2 = 0; nf2 < 2; ++nf2)
#pragma unroll
            for (int r = 0; r < 4; ++r) o[nf2][r] *= alpha[r];
#pragma unroll
        for (int r = 0; r < 4; ++r) lsum[r] = lsum[r] * alpha[r] + rsum[r];
        // P -> per-wave LDS (C-layout scatter), read back as A-frags
#pragma unroll
        for (int nf = 0; nf < 4; ++nf)
#pragma unroll
            for (int r = 0; r < 4; ++r)
                Pw[(quad * 4 + r) * 72 + nf * 16 + lrow] = f2b(ps[nf][r]);
#pragma unroll
        for (int kh = 0; kh < 2; ++kh) {
            bf16x8 pa = *(const bf16x8*)&Pw[lrow * 72 + kh * 32 + quad * 8];
#pragma unroll
            for (int nf2 = 0; nf2 < 2; ++nf2) {
                const int d = nf2 * 16 + lrow;
                bf16x8 vb = *(const bf16x8*)&VT[((int64_t)bh * 32 + d) * VLD + s0 + kh * 32 + quad * 8];
                o[nf2] = __builtin_amdgcn_mfma_f32_16x16x32_bf16(pa, vb, o[nf2], 0, 0, 0);
            }
        }
    }
#pragma unroll
    for (int r = 0; r < 4; ++r) {
        const int q = q0 + quad * 4 + r;
        if (q < 900) {
            const float inv = 1.f / lsum[r];
#pragma unroll
            for (int nf2 = 0; nf2 < 2; ++nf2)
                attno[((int64_t)(b * 900 + q)) * 256 + h * 32 + nf2 * 16 + lrow] = f2b(o[nf2][r] * inv);
        }
    }
}

// ---------------------------------------------------------------------------
// Residual + LayerNorm over C=256, one block per (b,t).
// MODE 0: res = query (B,C,PQ) fp32 transposed-read; out q1 fp32 + q1b bf16
// MODE 1: res = q1 fp32 (BT,C);                      out q2nb bf16 only
// MODE 2: res = q2nb bf16 (BT,C);                    out d_out fp32 (B,C,PQ)
// ---------------------------------------------------------------------------
template <int MODE>
__launch_bounds__(256)
__global__ void ln_kernel(const float* __restrict__ y, const void* __restrict__ res,
                          const float* __restrict__ g, const float* __restrict__ be,
                          float* __restrict__ out_f, short* __restrict__ out_b)
{
    const int bt = blockIdx.x;
    const int b = bt / PQ_, t = bt % PQ_;
    const int c = threadIdx.x;

    float r;
    if (MODE == 0)      r = ((const float*)res)[((int64_t)b * C_ + c) * PQ_ + t];
    else if (MODE == 1) r = ((const float*)res)[(int64_t)bt * C_ + c];
    else                r = b2f(((const short*)res)[(int64_t)bt * C_ + c]);
    const float v = r + y[(int64_t)bt * C_ + c];

    __shared__ float s1[256], s2[256];
    s1[c] = v; s2[c] = v * v;
    __syncthreads();
    for (int st = 128; st > 0; st >>= 1) {
        if (c < st) { s1[c] += s1[c + st]; s2[c] += s2[c + st]; }
        __syncthreads();
    }
    const float mean = s1[0] * (1.f / C_);
    const float var  = s2[0] * (1.f / C_) - mean * mean;
    const float o = (v - mean) * rsqrtf(var + 1e-5f) * g[c] + be[c];

    if (MODE == 0) { out_f[(int64_t)bt * C_ + c] = o; out_b[(int64_t)bt * C_ + c] = f2b(o); }
    else if (MODE == 1) out_b[(int64_t)bt * C_ + c] = f2b(o);
    else out_f[((int64_t)b * C_ + c) * PQ_ + t] = o;
}

// ---------------------------------------------------------------------------
// Fused MS-deformable sampling — all 4 levels in one kernel (known good).
// ---------------------------------------------------------------------------
__launch_bounds__(256)
__global__ void deform_kernel(const float* __restrict__ offb, const float* __restrict__ awl,
                              const float* __restrict__ refp, const short* __restrict__ value,
                              short* __restrict__ samp)
{
    const int bt = blockIdx.x;
    const int b = bt / PQ_;
    const int tid = threadIdx.x;
    const int h = tid >> 5, d = tid & 31;

    __shared__ float Loff[256];
    __shared__ float Law[128];
    __shared__ float Lref[8];

    Loff[tid] = offb[(int64_t)bt * 256 + tid];
    if (tid < 128) Law[tid] = awl[(int64_t)bt * 128 + tid];
    if (tid < 8)   Lref[tid] = refp[(int64_t)bt * 8 + tid];
    __syncthreads();

    float m = -1e30f;
#pragma unroll
    for (int i = 0; i < 16; ++i) m = fmaxf(m, Law[h * 16 + i]);
    float s = 0.f;
#pragma unroll
    for (int i = 0; i < 16; ++i) s += __expf(Law[h * 16 + i] - m);
    const float invs = 1.f / s;

    const int HLc[4] = {100, 50, 25, 13};
    const int WLc[4] = {152, 76, 38, 19};
    const int STc[4] = {0, 15200, 19000, 19950};

    float acc = 0.f;
#pragma unroll
    for (int l = 0; l < L_; ++l) {
        const int Hl = HLc[l], Wl = WLc[l], st0 = STc[l];
        const float fx = Lref[l * 2 + 0], fy = Lref[l * 2 + 1];
#pragma unroll
        for (int p = 0; p < P_; ++p) {
            const float ox = Loff[h * 32 + l * 8 + p * 2 + 0];
            const float oy = Loff[h * 32 + l * 8 + p * 2 + 1];
            const float x = (fx + ox / (float)Wl) * (float)Wl - 0.5f;
            const float y = (fy + oy / (float)Hl) * (float)Hl - 0.5f;
            const float x0f = floorf(x), y0f = floorf(y);
            const int x0 = (int)x0f, y0 = (int)y0f;
            const float lw = x - x0f, lh = y - y0f;
            const float w00 = (1.f - lw) * (1.f - lh), w10 = lw * (1.f - lh);
            const float w01 = (1.f - lw) * lh,         w11 = lw * lh;
            const float aww = __expf(Law[h * 16 + l * 4 + p] - m) * invs;

            float sv = 0.f;
            int ix, iy; float w;
#pragma unroll
            for (int cidx = 0; cidx < 4; ++cidx) {
                if (cidx == 0) { ix = x0;     iy = y0;     w = w00; }
                if (cidx == 1) { ix = x0 + 1; iy = y0;     w = w10; }
                if (cidx == 2) { ix = x0;     iy = y0 + 1; w = w01; }
                if (cidx == 3) { ix = x0 + 1; iy = y0 + 1; w = w11; }
                if (ix >= 0 && ix < Wl && iy >= 0 && iy < Hl) {
                    const int64_t vi = ((int64_t)(b * PK_ + st0 + iy * Wl + ix)) * 256 + h * 32 + d;
                    sv += w * b2f(value[vi]);
                }
            }
            acc += sv * aww;
        }
    }
    samp[(int64_t)bt * 256 + tid] = f2b(acc);
}

// ---------------------------------------------------------------------------
extern "C" void kernel_launch(void* const* d_in, const int* in_sizes, int n_in,
                              void* d_out, int out_size, void* d_ws, size_t ws_size,
                              hipStream_t stream)
{
    const float* query = (const float*)d_in[0];
    const float* key   = (const float*)d_in[1];
    const float* refp  = (const float*)d_in[4];
    const float* W_in  = (const float*)d_in[5];
    const float* b_in  = (const float*)d_in[6];
    const float* W_out = (const float*)d_in[7];
    const float* b_out = (const float*)d_in[8];
    const float* W_off = (const float*)d_in[9];
    const float* b_off = (const float*)d_in[10];
    const float* W_aw  = (const float*)d_in[11];
    const float* b_aw  = (const float*)d_in[12];
    const float* W_v   = (const float*)d_in[13];
    const float* b_v   = (const float*)d_in[14];
    const float* W_o   = (const float*)d_in[15];
    const float* b_o   = (const float*)d_in[16];
    const float* W1    = (const float*)d_in[17];
    const float* b1    = (const float*)d_in[18];
    const float* W2    = (const float*)d_in[19];
    const float* b2    = (const float*)d_in[20];
    const float* g1    = (const float*)d_in[21];
    const float* be1   = (const float*)d_in[22];
    const float* g2    = (const float*)d_in[23];
    const float* be2   = (const float*)d_in[24];
    const float* g3    = (const float*)d_in[25];
    const float* be3   = (const float*)d_in[26];

    // Workspace plan:
    //  X [62,259,200]: {qkv bf16 | queryT | VT | attno} -> later ffh
    //  Y: proj -> offb -> proj2 -> ffo ; Z1: q1 ; Wa: q1b -> samp ; Wb: awl -> q2nb
    //  KT:  keyT  (B*PK,256) bf16 ; VA: value (B*PK,256) bf16
    //  WB:  all weights converted to bf16 (1,540,096 elems = 3,080,192 B)
    char* X  = (char*)d_ws;
    char* Yb = X + 62259200;
    char* Z1 = Yb + 7372800;
    char* Wa = Z1 + 7372800;
    char* Wb_ = Wa + 3686400;
    char* KT = Wb_ + 3686400;
    char* VA = KT + 82726912;
    char* WB = VA + 82726912;

    short* qkvb   = (short*)X;                 // (B*900, 768) bf16
    short* queryT = (short*)(X + 11059200);
    short* VT     = (short*)(X + 14745600);    // 64*32*960*2 = 3,932,160
    short* attno  = (short*)(X + 18677760);
    short* ffh    = (short*)X;
    float* proj   = (float*)Yb;
    float* offb   = (float*)Yb;
    float* proj2  = (float*)Yb;
    float* ffo    = (float*)Yb;
    float* q1     = (float*)Z1;
    short* q1b    = (short*)Wa;
    short* samp   = (short*)Wa;
    float* awl    = (float*)Wb_;
    short* q2nb   = (short*)Wb_;
    short* keyT   = (short*)KT;
    short* value  = (short*)VA;

    short* WBs    = (short*)WB;
    short* Wb_in  = WBs;             // 196608
    short* Wb_out = WBs + 196608;    // 65536
    short* Wb_off = WBs + 262144;    // 65536
    short* Wb_aw  = WBs + 327680;    // 32768
    short* Wb_v   = WBs + 360448;    // 65536
    short* Wb_o   = WBs + 425984;    // 65536
    short* Wb1    = WBs + 491520;    // 524288
    short* Wb2    = WBs + 1015808;   // 524288

    // 0. convert all weights fp32 -> bf16 (one launch)
    wcvt_kernel<<<1504, 256, 0, stream>>>(W_in, W_out, W_off, W_aw, W_v, W_o, W1, W2, WBs);
    // 1. queryT = bf16 transpose of query
    transpose_kernel<<<dim3(29, 8, B_), 256, 0, stream>>>(query, queryT, PQ_, PQ_,
                                                          (int64_t)C_ * PQ_, (int64_t)PQ_ * C_);
    // 2. qkv = queryT @ W_in^T + b_in  (bf16 out)
    mfma_launch<1, true, false, false, false, false>(queryT, Wb_in, b_in, qkvb, 1, 1, B_ * PQ_, 768, 256,
                                                     256, 256, 768, 0, 0, 0, 0, 0, 0, 1.f, stream);
    // 3. VT (zero-padded to 960)
    vt_kernel<<<dim3(30, 64), 256, 0, stream>>>(qkvb, VT);
    // 4. fused flash attention -> attno (bf16)
    attn_fused<<<dim3(15, 64), 256, 0, stream>>>(qkvb, VT, attno);
    // 5. proj = attno @ W_out^T + b_out
    mfma_launch<1, true, false, false, true, false>(attno, Wb_out, b_out, proj, 1, 1, B_ * PQ_, 256, 256,
                                                    256, 256, 256, 0, 0, 0, 0, 0, 0, 1.f, stream);
    // 6. q1 = LN(x + proj)  (fp32 + bf16)
    ln_kernel<0><<<B_ * PQ_, 256, 0, stream>>>(proj, query, g1, be1, q1, q1b);
    // 7. offsets / attention-weight logits
    mfma_launch<1, true, false, false, true, false>(q1b, Wb_off, b_off, offb, 1, 1, B_ * PQ_, 256, 256,
                                                    256, 256, 256, 0, 0, 0, 0, 0, 0, 1.f, stream);
    mfma_launch<1, true, false, false, true, false>(q1b, Wb_aw, b_aw, awl, 1, 1, B_ * PQ_, 128, 256,
                                                    256, 256, 128, 0, 0, 0, 0, 0, 0, 1.f, stream);
    // 8. keyT = bf16 transpose of ALL of key; value = keyT @ W_v^T + b_v
    //    (W-resident barrier-free streaming kernel); fused 4-level deform
    transpose_kernel<<<dim3((PK_ + 31) / 32, 8, B_), 256, 0, stream>>>(
        key, keyT, PK_, PK_, (int64_t)C_ * PK_, (int64_t)PK_ * 256);
    {
        const int nTiles = (B_ * PK_ + 63) / 64;          // 2525
        vproj_kernel<<<dim3(2, (nTiles + 3) / 4), 256, 0, stream>>>(
            keyT, Wb_v, b_v, value, B_ * PK_, nTiles);
    }
    deform_kernel<<<B_ * PQ_, 256, 0, stream>>>(offb, awl, refp, value, samp);
    // 9. proj2 = samp @ W_o^T + b_o
    mfma_launch<1, true, false, false, true, false>(samp, Wb_o, b_o, proj2, 1, 1, B_ * PQ_, 256, 256,
                                                    256, 256, 256, 0, 0, 0, 0, 0, 0, 1.f, stream);
    // 10. q2nb = LN(q1 + proj2)  (bf16)
    ln_kernel<1><<<B_ * PQ_, 256, 0, stream>>>(proj2, q1, g2, be2, nullptr, q2nb);
    // 11. ffh = relu(q2nb @ W1^T + b1)  (bf16)
    mfma_launch<1, true, false, false, false, true>(q2nb, Wb1, b1, ffh, 1, 1, B_ * PQ_, FF_, 256,
                                                    256, 256, FF_, 0, 0, 0, 0, 0, 0, 1.f, stream);
    // 12. ffo = ffh @ W2^T + b2
    mfma_launch<1, true, false, false, true, false>(ffh, Wb2, b2, ffo, 1, 1, B_ * PQ_, 256, FF_,
                                                    FF_, FF_, 256, 0, 0, 0, 0, 0, 0, 1.f, stream);
    // 13. d_out = LN(q2nb + ffo), transposed to (B,C,PQ)
    ln_kernel<2><<<B_ * PQ_, 256, 0, stream>>>(ffo, q2nb, g3, be3, (float*)d_out, nullptr);

    (void)in_sizes; (void)n_in; (void)out_size; (void)ws_size;
}